// Round 10
// baseline (274.197 us; speedup 1.0000x reference)
//
#include <hip/hip_runtime.h>
#include <cmath>

// Problem dims
#define TN 4
#define TC1 256
#define TCH 128
#define TC2 256
#define TH 80
#define TW 80
#define THP 82
#define TWP 84
#define NPIX (TN*TH*TW)   // 25600

// Workspace layout (float offsets). Total = 17,356,288 floats = 69.4 MB.
#define OFF_WBF   0         // bf16 wbf[co][tap*256+ci], s1-folded: 294912 shorts
#define OFF_W2B   294912    // bf16 [co][ci=128], s2-folded: 32768 shorts
#define OFF_INWB  327680    // bf16 [co][ci=256]: 65536 shorts
#define OFF_OUTWB 393216    // bf16 [co][ci=256], s3-folded: 65536 shorts
#define OFF_DWT   458752    // fp32 [tap][c] 2304
#define OFF_WCAT  461056    // bf16 [j<32][c=256] 8192 shorts
#define OFF_WCATB 467968    // fp32 27
#define OFF_T1    468128    // 128
#define OFF_T2    468512    // 256
#define OFF_T3P   469024    // 256
#define OFF_XPAD  469504    // bf16 NHWC padded x: ends 3,997,696
#define OFF_Y1B   3997696   // bf16 y1 [25600][128]: ends 5,636,096
#define OFF_Y1P   7525888   // fp32 cv1 partials [3][25600][128]: ends 17,356,288
// aliases (liveness chain, stream order) — unchanged:
#define OFF_Y2N   7525888   // bf16 y2 [25600][256] (partials dead after y1red)
#define OFF_DWN   469504    // bf16 dw [25600][256] (xpad dead after cv1)
#define OFF_RAWN  10802688  // fp32 raw [25600][27]
#define OFF_ZN    11493888  // bf16 z [25600][256]

typedef __attribute__((ext_vector_type(8))) short bf16x8;
typedef __attribute__((ext_vector_type(4))) float f32x4;

__device__ __forceinline__ float siluf(float v) { return v / (1.f + expf(-v)); }
__device__ __forceinline__ short rnbf(float f) {
  unsigned u = __float_as_uint(f);
  unsigned r = (u + 0x7fffu + ((u >> 16) & 1u)) >> 16;
  return (short)r;
}
__device__ __forceinline__ float bf2f(short s) {
  return __uint_as_float(((unsigned)(unsigned short)s) << 16);
}

// async global->LDS, 16B per lane; LDS dest = wave-uniform base + lane*16B
typedef __attribute__((address_space(1))) const unsigned int guint_t;
typedef __attribute__((address_space(3))) unsigned int luint_t;
__device__ __forceinline__ void gl2lds16(const short* g, short* l) {
  __builtin_amdgcn_global_load_lds((guint_t*)g, (luint_t*)l, 16, 0, 0);
}

// ---------------- prep: weight transposes + BN constant folding ----------------
__global__ __launch_bounds__(256) void k_prep(
    const float* __restrict__ w1, const float* __restrict__ g1, const float* __restrict__ b1,
    const float* __restrict__ m1, const float* __restrict__ v1,
    const float* __restrict__ w2, const float* __restrict__ g2, const float* __restrict__ b2,
    const float* __restrict__ m2, const float* __restrict__ v2,
    const float* __restrict__ dww, const float* __restrict__ offw, const float* __restrict__ offb,
    const float* __restrict__ mskw, const float* __restrict__ mskb,
    const float* __restrict__ inw, const float* __restrict__ outw, const float* __restrict__ outb,
    const float* __restrict__ g3, const float* __restrict__ b3,
    const float* __restrict__ m3, const float* __restrict__ v3,
    float* __restrict__ ws)
{
  int i = blockIdx.x * 256 + threadIdx.x;
  if (i < 294912) {
    int co = i / 2304; int r = i - co * 2304;
    int tap = r >> 8; int ci = r & 255; int ky = tap / 3; int kx = tap - ky * 3;
    float s = g1[co] * __frsqrt_rn(v1[co] + 1e-5f);
    ((short*)(ws + OFF_WBF))[i] = rnbf(w1[((co * TC1 + ci) * 3 + ky) * 3 + kx] * s);
    return;
  }
  i -= 294912;
  if (i < 32768) {
    int co = i >> 7; int ci = i & 127;
    float s = g2[co] * __frsqrt_rn(v2[co] + 1e-5f);
    ((short*)(ws + OFF_W2B))[i] = rnbf(w2[co * TCH + ci] * s);
    return;
  }
  i -= 32768;
  if (i < 65536) {
    int co = i >> 8; int ci = i & 255;
    ((short*)(ws + OFF_INWB))[i] = rnbf(inw[co * TC2 + ci]);
    return;
  }
  i -= 65536;
  if (i < 65536) {
    int co = i >> 8; int ci = i & 255;
    float s = g3[co] * __frsqrt_rn(v3[co] + 1e-5f);
    ((short*)(ws + OFF_OUTWB))[i] = rnbf(outw[co * TC2 + ci] * s);
    return;
  }
  i -= 65536;
  if (i < 2304) { int c = i & 255; int j = i >> 8; ws[OFF_DWT + i] = dww[c * 9 + j]; return; }
  i -= 2304;
  if (i < 8192) {
    int c = i & 255; int j = i >> 8;
    float v = 0.f;
    if (j < 18) v = offw[j * 256 + c];
    else if (j < 27) v = mskw[(j - 18) * 256 + c];
    ((short*)(ws + OFF_WCAT))[i] = rnbf(v);
    return;
  }
  i -= 8192;
  if (i < 27) { ws[OFF_WCATB + i] = (i < 18) ? offb[i] : mskb[i - 18]; return; }
  i -= 27;
  if (i < 128) { float s = g1[i] / sqrtf(v1[i] + 1e-5f); ws[OFF_T1 + i] = b1[i] - m1[i] * s; return; }
  i -= 128;
  if (i < 256) { float s = g2[i] / sqrtf(v2[i] + 1e-5f); ws[OFF_T2 + i] = b2[i] - m2[i] * s; return; }
  i -= 256;
  if (i < 256) { float s = g3[i] / sqrtf(v3[i] + 1e-5f); ws[OFF_T3P + i] = outb[i] * s + b3[i] - m3[i] * s; return; }
}

// ---------------- x -> bf16 NHWC padded [4][82][84][256], zero halo (vectorized) ----------------
__global__ __launch_bounds__(256) void k_padx(const float* __restrict__ x, short* __restrict__ xpn)
{
  __shared__ short lds[80 * 40];
  int b = blockIdx.x;
  int cc = b & 7; int hp = (b >> 3) % THP; int n = b / (THP * 8);
  int c0 = cc * 32;
  int t = threadIdx.x;
  int h = hp - 1;
  bool hv = (h >= 0 && h < TH);
  if (hv) {
    for (int f = t; f < 640; f += 256) {
      int ci = f / 20; int w4 = (f - ci * 20) * 4;
      float4 xv = *(const float4*)(x + ((n * TC1 + c0 + ci) * TH + h) * TW + w4);
      lds[(w4 + 0) * 40 + ci] = rnbf(xv.x);
      lds[(w4 + 1) * 40 + ci] = rnbf(xv.y);
      lds[(w4 + 2) * 40 + ci] = rnbf(xv.z);
      lds[(w4 + 3) * 40 + ci] = rnbf(xv.w);
    }
  }
  __syncthreads();
  short* op = xpn + ((n * THP + hp) * TWP) * TC2 + c0;
  for (int g = t; g < 672; g += 256) {
    int ci4 = (g & 7) * 4; int wp = g >> 3;
    short4 v = {0, 0, 0, 0};
    if (hv && wp >= 1 && wp <= TW) v = *(const short4*)(&lds[(wp - 1) * 40 + ci4]);
    *(short4*)(op + wp * TC2 + ci4) = v;
  }
}

// ---------------- cv1: async-LDS double-buffered bf16 MFMA implicit-GEMM ----------------
// grid 600; tile 128co x 128px, K-split x3 (3 taps each). Per 32-ci chunk: 16x global_load_lds
// dwordx4 (block), piece-swizzled LDS (slot l <-> row l&15, piece (l>>4)^(l&3)), 1 barrier/chunk.
__global__ __launch_bounds__(256) void k_cv1(const short* __restrict__ xpn, const short* __restrict__ wbf,
                                             float* __restrict__ y1p)
{
  __shared__ short As[2][4096] __attribute__((aligned(16)));   // 8 segments x 512 shorts
  __shared__ short Bs[2][4096] __attribute__((aligned(16)));

  int b = blockIdx.x;
  int wt = b % 5; b /= 5; int ht = b % 10; b /= 10; int n = b & 3; int ks = b >> 2;
  int w0 = wt * 16, h0 = ht * 8;
  int tap0 = ks * 3;

  int tid = threadIdx.x;
  int wave = tid >> 6, lane = tid & 63;
  int ln = lane & 15, q = lane >> 4;
  int cohalf = (wave & 1) * 64;
  int pxhalf = (wave >> 1) * 64;

  int lr = lane & 15;                          // row within segment
  int lp = ((lane >> 4) ^ (lane & 3)) * 8;     // swizzled global piece (shorts)

  f32x4 acc[4][4];
#pragma unroll
  for (int i = 0; i < 4; ++i)
#pragma unroll
    for (int j = 0; j < 4; ++j) acc[i][j] = (f32x4){0.f, 0.f, 0.f, 0.f};

  auto stage = [&](int c, int buf) {
    int rt = c >> 3;
    int atap = tap0 + rt;
    int ci0 = (c & 7) * 32;
    int ky = atap / 3, kx = atap - ky * 3;
#pragma unroll
    for (int i = 0; i < 4; ++i) {
      int seg = wave * 4 + i;
      if (seg < 8) {
        const short* g = wbf + (seg * 16 + lr) * 2304 + atap * 256 + ci0 + lp;
        gl2lds16(g, &As[buf][seg * 512]);
      } else {
        int s = seg - 8;
        const short* g = xpn + (((n * THP + h0 + s + ky) * TWP) + (w0 + lr + kx)) * 256 + ci0 + lp;
        gl2lds16(g, &Bs[buf][s * 512]);
      }
    }
  };
  auto comp = [&](int buf) {
    int xo = ((q ^ (ln & 3)) * 16 + ln) * 8;   // swizzled slot within segment (shorts)
    bf16x8 af[4], bfv[4];
#pragma unroll
    for (int mt = 0; mt < 4; ++mt)
      af[mt] = *(const bf16x8*)(&As[buf][((cohalf >> 4) + mt) * 512 + xo]);
#pragma unroll
    for (int nt = 0; nt < 4; ++nt)
      bfv[nt] = *(const bf16x8*)(&Bs[buf][((pxhalf >> 4) + nt) * 512 + xo]);
#pragma unroll
    for (int mt = 0; mt < 4; ++mt)
#pragma unroll
      for (int nt = 0; nt < 4; ++nt)
        acc[mt][nt] = __builtin_amdgcn_mfma_f32_16x16x32_bf16(af[mt], bfv[nt], acc[mt][nt], 0, 0, 0);
  };

  stage(0, 0);
  __syncthreads();                     // implicit vmcnt(0) drain: chunk 0 in LDS
  for (int c = 0; c < 24; ++c) {
    if (c < 23) stage(c + 1, (c + 1) & 1);
    comp(c & 1);
    if (c < 23) __syncthreads();       // drains DMA of c+1; protects buffer reuse
  }

  float* yp = y1p + ks * (NPIX * TCH);
#pragma unroll
  for (int mt = 0; mt < 4; ++mt)
#pragma unroll
    for (int nt = 0; nt < 4; ++nt) {
      int p = pxhalf + nt * 16 + ln;
      int pr = p >> 4, pc = p & 15;
      int pix = (n * TH + h0 + pr) * TW + (w0 + pc);
      int co = cohalf + mt * 16 + q * 4;
      *(f32x4*)(yp + pix * TCH + co) = acc[mt][nt];
    }
}

// ---------------- y1 reduce: silu(p0+p1+p2+t1) -> bf16 NHWC ----------------
__global__ __launch_bounds__(256) void k_y1red(const float* __restrict__ y1p, const float* __restrict__ t1v,
                                               short* __restrict__ y1b)
{
  int i = blockIdx.x * 256 + threadIdx.x;
  int co4 = (i & 31) * 4;
  int pix = i >> 5;
  float4 a = *(const float4*)(y1p + pix * TCH + co4);
  float4 bq = *(const float4*)(y1p + NPIX * TCH + pix * TCH + co4);
  float4 cq = *(const float4*)(y1p + 2 * NPIX * TCH + pix * TCH + co4);
  float4 t = *(const float4*)(t1v + co4);
  short4 o;
  o.x = rnbf(siluf(a.x + bq.x + cq.x + t.x));
  o.y = rnbf(siluf(a.y + bq.y + cq.y + t.y));
  o.z = rnbf(siluf(a.z + bq.z + cq.z + t.z));
  o.w = rnbf(siluf(a.w + bq.w + cq.w + t.w));
  *(short4*)(y1b + pix * TCH + co4) = o;
}

// ---------------- cv2: async-LDS bf16 MFMA GEMM 128->256 + BN + SiLU ----------------
// grid 400 = 200 px-tiles x 2 co-halves; K=128 (4 chunks)
__global__ __launch_bounds__(256) void k_cv2(const short* __restrict__ y1b, const short* __restrict__ w2b,
                                             const float* __restrict__ t2v, short* __restrict__ y2b)
{
  __shared__ short As[2][4096] __attribute__((aligned(16)));
  __shared__ short Bs[2][4096] __attribute__((aligned(16)));

  int b = blockIdx.x;
  int ch = b & 1; int pt = b >> 1;
  int co_base = ch * 128;
  int pix0 = pt * 128;

  int tid = threadIdx.x;
  int wave = tid >> 6, lane = tid & 63;
  int ln = lane & 15, q = lane >> 4;
  int coh = (wave & 1) * 64;
  int pxh = (wave >> 1) * 64;

  int lr = lane & 15;
  int lp = ((lane >> 4) ^ (lane & 3)) * 8;

  f32x4 acc[4][4];
#pragma unroll
  for (int i = 0; i < 4; ++i)
#pragma unroll
    for (int j = 0; j < 4; ++j) acc[i][j] = (f32x4){0.f, 0.f, 0.f, 0.f};

  auto stage = [&](int c, int buf) {
#pragma unroll
    for (int i = 0; i < 4; ++i) {
      int seg = wave * 4 + i;
      if (seg < 8) {
        const short* g = w2b + (co_base + seg * 16 + lr) * TCH + c * 32 + lp;
        gl2lds16(g, &As[buf][seg * 512]);
      } else {
        int s = seg - 8;
        const short* g = y1b + (pix0 + s * 16 + lr) * TCH + c * 32 + lp;
        gl2lds16(g, &Bs[buf][s * 512]);
      }
    }
  };
  auto comp = [&](int buf) {
    int xo = ((q ^ (ln & 3)) * 16 + ln) * 8;
    bf16x8 af[4], bfv[4];
#pragma unroll
    for (int mt = 0; mt < 4; ++mt)
      af[mt] = *(const bf16x8*)(&As[buf][((coh >> 4) + mt) * 512 + xo]);
#pragma unroll
    for (int nt = 0; nt < 4; ++nt)
      bfv[nt] = *(const bf16x8*)(&Bs[buf][((pxh >> 4) + nt) * 512 + xo]);
#pragma unroll
    for (int mt = 0; mt < 4; ++mt)
#pragma unroll
      for (int nt = 0; nt < 4; ++nt)
        acc[mt][nt] = __builtin_amdgcn_mfma_f32_16x16x32_bf16(af[mt], bfv[nt], acc[mt][nt], 0, 0, 0);
  };

  const int NCH = TCH / 32;
  stage(0, 0);
  __syncthreads();
  for (int c = 0; c < NCH; ++c) {
    if (c < NCH - 1) stage(c + 1, (c + 1) & 1);
    comp(c & 1);
    if (c < NCH - 1) __syncthreads();
  }

#pragma unroll
  for (int mt = 0; mt < 4; ++mt) {
    int co = co_base + coh + mt * 16 + q * 4;
    float t0 = t2v[co], t1 = t2v[co + 1], t2 = t2v[co + 2], t3 = t2v[co + 3];
#pragma unroll
    for (int nt = 0; nt < 4; ++nt) {
      int pix = pix0 + pxh + nt * 16 + ln;
      short4 p;
      p.x = rnbf(siluf(acc[mt][nt][0] + t0));
      p.y = rnbf(siluf(acc[mt][nt][1] + t1));
      p.z = rnbf(siluf(acc[mt][nt][2] + t2));
      p.w = rnbf(siluf(acc[mt][nt][3] + t3));
      *(short4*)(y2b + pix * TC2 + co) = p;
    }
  }
}

// ---------------- input_proj: async-LDS bf16 MFMA GEMM 256->256 + bias ----------------
__global__ __launch_bounds__(256) void k_proj_in(const short* __restrict__ y2b, const short* __restrict__ inwb,
                                                 const float* __restrict__ inb, short* __restrict__ xproj)
{
  __shared__ short As[2][4096] __attribute__((aligned(16)));
  __shared__ short Bs[2][4096] __attribute__((aligned(16)));

  int b = blockIdx.x;
  int ch = b & 1; int pt = b >> 1;
  int co_base = ch * 128;
  int pix0 = pt * 128;

  int tid = threadIdx.x;
  int wave = tid >> 6, lane = tid & 63;
  int ln = lane & 15, q = lane >> 4;
  int coh = (wave & 1) * 64;
  int pxh = (wave >> 1) * 64;

  int lr = lane & 15;
  int lp = ((lane >> 4) ^ (lane & 3)) * 8;

  f32x4 acc[4][4];
#pragma unroll
  for (int i = 0; i < 4; ++i)
#pragma unroll
    for (int j = 0; j < 4; ++j) acc[i][j] = (f32x4){0.f, 0.f, 0.f, 0.f};

  auto stage = [&](int c, int buf) {
#pragma unroll
    for (int i = 0; i < 4; ++i) {
      int seg = wave * 4 + i;
      if (seg < 8) {
        const short* g = inwb + (co_base + seg * 16 + lr) * TC2 + c * 32 + lp;
        gl2lds16(g, &As[buf][seg * 512]);
      } else {
        int s = seg - 8;
        const short* g = y2b + (pix0 + s * 16 + lr) * TC2 + c * 32 + lp;
        gl2lds16(g, &Bs[buf][s * 512]);
      }
    }
  };
  auto comp = [&](int buf) {
    int xo = ((q ^ (ln & 3)) * 16 + ln) * 8;
    bf16x8 af[4], bfv[4];
#pragma unroll
    for (int mt = 0; mt < 4; ++mt)
      af[mt] = *(const bf16x8*)(&As[buf][((coh >> 4) + mt) * 512 + xo]);
#pragma unroll
    for (int nt = 0; nt < 4; ++nt)
      bfv[nt] = *(const bf16x8*)(&Bs[buf][((pxh >> 4) + nt) * 512 + xo]);
#pragma unroll
    for (int mt = 0; mt < 4; ++mt)
#pragma unroll
      for (int nt = 0; nt < 4; ++nt)
        acc[mt][nt] = __builtin_amdgcn_mfma_f32_16x16x32_bf16(af[mt], bfv[nt], acc[mt][nt], 0, 0, 0);
  };

  const int NCH = TC2 / 32;
  stage(0, 0);
  __syncthreads();
  for (int c = 0; c < NCH; ++c) {
    if (c < NCH - 1) stage(c + 1, (c + 1) & 1);
    comp(c & 1);
    if (c < NCH - 1) __syncthreads();
  }

#pragma unroll
  for (int mt = 0; mt < 4; ++mt) {
    int co = co_base + coh + mt * 16 + q * 4;
    float b0 = inb[co], b1 = inb[co + 1], b2 = inb[co + 2], b3 = inb[co + 3];
#pragma unroll
    for (int nt = 0; nt < 4; ++nt) {
      int pix = pix0 + pxh + nt * 16 + ln;
      short4 p;
      p.x = rnbf(acc[mt][nt][0] + b0);
      p.y = rnbf(acc[mt][nt][1] + b1);
      p.z = rnbf(acc[mt][nt][2] + b2);
      p.w = rnbf(acc[mt][nt][3] + b3);
      *(short4*)(xproj + pix * TC2 + co) = p;
    }
  }
}

// ---------------- depthwise 3x3 + bias + LN + GELU: 2 px/wave, 8 ch/lane ----------------
__global__ __launch_bounds__(256) void k_dwln(const short* __restrict__ y2b, const float* __restrict__ dwt,
                                              const float* __restrict__ dwb, const float* __restrict__ lng,
                                              const float* __restrict__ lnb, short* __restrict__ dwo)
{
  int tid = threadIdx.x;
  int wave = tid >> 6, lane = tid & 63;
  int half = lane >> 5;
  int pix = blockIdx.x * 8 + wave * 2 + half;
  int w = pix % TW; int h = (pix / TW) % TH; int n = pix / (TH * TW);
  int c0 = (lane & 31) * 8;

  float v[8];
  {
    float4 b0 = *(const float4*)(dwb + c0);
    float4 b1 = *(const float4*)(dwb + c0 + 4);
    v[0] = b0.x; v[1] = b0.y; v[2] = b0.z; v[3] = b0.w;
    v[4] = b1.x; v[5] = b1.y; v[6] = b1.z; v[7] = b1.w;
  }
#pragma unroll
  for (int dy = 0; dy < 3; ++dy) {
#pragma unroll
    for (int dx = 0; dx < 3; ++dx) {
      int hh = h + dy - 1, ww = w + dx - 1;
      bool ok = (hh >= 0) & (hh < TH) & (ww >= 0) & (ww < TW);
      int off = ok ? (((n * TH + hh) * TW + ww) * TC2 + c0) : c0;
      bf16x8 yv = *(const bf16x8*)(y2b + off);
      float m = ok ? 1.f : 0.f;
      const float* wp = dwt + (dy * 3 + dx) * TC2 + c0;
      float4 w0 = *(const float4*)(wp);
      float4 w1 = *(const float4*)(wp + 4);
      v[0] += bf2f(yv[0]) * w0.x * m;
      v[1] += bf2f(yv[1]) * w0.y * m;
      v[2] += bf2f(yv[2]) * w0.z * m;
      v[3] += bf2f(yv[3]) * w0.w * m;
      v[4] += bf2f(yv[4]) * w1.x * m;
      v[5] += bf2f(yv[5]) * w1.y * m;
      v[6] += bf2f(yv[6]) * w1.z * m;
      v[7] += bf2f(yv[7]) * w1.w * m;
    }
  }
  float sv = 0.f, sq = 0.f;
#pragma unroll
  for (int i = 0; i < 8; ++i) { sv += v[i]; sq += v[i] * v[i]; }
#pragma unroll
  for (int o = 16; o > 0; o >>= 1) { sv += __shfl_xor(sv, o); sq += __shfl_xor(sq, o); }
  float mu = sv * (1.f / 256.f);
  float var = sq * (1.f / 256.f) - mu * mu;
  float rs = 1.f / sqrtf(var + 1e-6f);
  float4 g0 = *(const float4*)(lng + c0);
  float4 g1 = *(const float4*)(lng + c0 + 4);
  float4 bb0 = *(const float4*)(lnb + c0);
  float4 bb1 = *(const float4*)(lnb + c0 + 4);
  float gv[8] = {g0.x, g0.y, g0.z, g0.w, g1.x, g1.y, g1.z, g1.w};
  float bv[8] = {bb0.x, bb0.y, bb0.z, bb0.w, bb1.x, bb1.y, bb1.z, bb1.w};
  const float is2 = 0.70710678118654752f;
  bf16x8 o8;
#pragma unroll
  for (int i = 0; i < 8; ++i) {
    float nv = (v[i] - mu) * rs * gv[i] + bv[i];
    o8[i] = rnbf(0.5f * nv * (1.f + erff(nv * is2)));
  }
  *(bf16x8*)(dwo + pix * TC2 + c0) = o8;
}

// ---------------- offset/mask logits via MFMA ----------------
__global__ __launch_bounds__(256) void k_offmask(const short* __restrict__ dwo, const short* __restrict__ wcatb16,
                                                 const float* __restrict__ wcatb, float* __restrict__ raw)
{
  int tid = threadIdx.x;
  int wave = tid >> 6, lane = tid & 63;
  int ln = lane & 15, q = lane >> 4;
  int pix0 = blockIdx.x * 64 + wave * 16;

  f32x4 acc0 = {0.f, 0.f, 0.f, 0.f};
  f32x4 acc1 = acc0;

  const short* a0p = wcatb16 + ln * 256 + q * 8;
  const short* a1p = wcatb16 + (16 + ln) * 256 + q * 8;
  const short* bp  = dwo + (pix0 + ln) * 256 + q * 8;
#pragma unroll
  for (int kk = 0; kk < 256; kk += 32) {
    bf16x8 bf = *(const bf16x8*)(bp + kk);
    bf16x8 a0 = *(const bf16x8*)(a0p + kk);
    bf16x8 a1 = *(const bf16x8*)(a1p + kk);
    acc0 = __builtin_amdgcn_mfma_f32_16x16x32_bf16(a0, bf, acc0, 0, 0, 0);
    acc1 = __builtin_amdgcn_mfma_f32_16x16x32_bf16(a1, bf, acc1, 0, 0, 0);
  }

  int pix = pix0 + ln;
#pragma unroll
  for (int r = 0; r < 4; ++r) {
    int j0 = q * 4 + r;
    raw[pix * 27 + j0] = acc0[r] + wcatb[j0];
    int j1 = 16 + j0;
    if (j1 < 27) raw[pix * 27 + j1] = acc1[r] + wcatb[j1];
  }
}

// ---------------- DCN core: 8 px/block setup, 2 px/wave, 8 ch/lane ----------------
__global__ __launch_bounds__(256) void k_dcn(const short* __restrict__ xproj, const float* __restrict__ raw,
                                             short* __restrict__ z)
{
  __shared__ int2 sp[8][36];
  int tid = threadIdx.x;
  int pixbase = blockIdx.x * 8;

  for (int j = tid; j < 288; j += 256) {
    int pxl = j / 36, t = j - pxl * 36;
    int pix = pixbase + pxl;
    int w = pix % TW; int h = (pix / TW) % TH;
    const float* r = raw + pix * 27;
    int k = t >> 2, tap = t & 3;
    int tx = tap & 1, ty = tap >> 1;
    float mx = r[18];
#pragma unroll
    for (int kk = 1; kk < 9; ++kk) mx = fmaxf(mx, r[18 + kk]);
    float sum = 0.f, ek = 0.f;
#pragma unroll
    for (int kk = 0; kk < 9; ++kk) {
      float ee = expf(r[18 + kk] - mx);
      sum += ee;
      if (kk == k) ek = ee;
    }
    float mk = ek / sum;
    float px = (float)(w + k / 3) + r[2 * k];
    float py = (float)(h + k % 3) + r[2 * k + 1];
    float x0f = floorf(px), y0f = floorf(py);
    float lw = px - x0f, lh = py - y0f;
    int x0 = (int)x0f + tx, y0 = (int)y0f + ty;
    float wt = mk * (tx ? lw : 1.f - lw) * (ty ? lh : 1.f - lh);
    bool valid = (x0 >= 1) & (x0 <= TW) & (y0 >= 1) & (y0 <= TH);
    int2 pr;
    pr.x = valid ? (((y0 - 1) * TW + (x0 - 1)) * TC2) : 0;
    pr.y = valid ? __float_as_int(wt) : 0;
    sp[pxl][t] = pr;
  }
  __syncthreads();

  int wave = tid >> 6, lane = tid & 63;
  int half = lane >> 5;
  int pxl = wave * 2 + half;
  int pix = pixbase + pxl;
  int n = pix / (TH * TW);
  int c0 = (lane & 31) * 8;
  const short* xb = xproj + n * (TH * TW * TC2) + c0;

  float a[8] = {0.f, 0.f, 0.f, 0.f, 0.f, 0.f, 0.f, 0.f};
#pragma unroll
  for (int t = 0; t < 36; ++t) {
    int2 pr = sp[pxl][t];
    float wt = __int_as_float(pr.y);
    bf16x8 v = *(const bf16x8*)(xb + pr.x);
#pragma unroll
    for (int i = 0; i < 8; ++i) a[i] += wt * bf2f(v[i]);
  }
  bf16x8 o8;
#pragma unroll
  for (int i = 0; i < 8; ++i) o8[i] = rnbf(a[i]);
  *(bf16x8*)(z + pix * TC2 + c0) = o8;
}

// ---------------- output_proj: async-LDS MFMA + BN + SiLU + residual -> d_out NCHW fp32 ----------------
__global__ __launch_bounds__(256) void k_proj_out(const short* __restrict__ zb, const short* __restrict__ outwb,
                                                  const float* __restrict__ t3p,
                                                  const float* __restrict__ x, float* __restrict__ out)
{
  __shared__ short As[2][4096] __attribute__((aligned(16)));
  __shared__ short Bs[2][4096] __attribute__((aligned(16)));

  int b = blockIdx.x;
  int ch = b & 1; int pt = b >> 1;
  int co_base = ch * 128;
  int pix0 = pt * 128;

  int tid = threadIdx.x;
  int wave = tid >> 6, lane = tid & 63;
  int ln = lane & 15, q = lane >> 4;
  int coh = (wave & 1) * 64;
  int pxh = (wave >> 1) * 64;

  int lr = lane & 15;
  int lp = ((lane >> 4) ^ (lane & 3)) * 8;

  f32x4 acc[4][4];
#pragma unroll
  for (int i = 0; i < 4; ++i)
#pragma unroll
    for (int j = 0; j < 4; ++j) acc[i][j] = (f32x4){0.f, 0.f, 0.f, 0.f};

  auto stage = [&](int c, int buf) {
#pragma unroll
    for (int i = 0; i < 4; ++i) {
      int seg = wave * 4 + i;
      if (seg < 8) {
        const short* g = outwb + (co_base + seg * 16 + lr) * TC2 + c * 32 + lp;
        gl2lds16(g, &As[buf][seg * 512]);
      } else {
        int s = seg - 8;
        const short* g = zb + (pix0 + s * 16 + lr) * TC2 + c * 32 + lp;
        gl2lds16(g, &Bs[buf][s * 512]);
      }
    }
  };
  auto comp = [&](int buf) {
    int xo = ((q ^ (ln & 3)) * 16 + ln) * 8;
    bf16x8 af[4], bfv[4];
#pragma unroll
    for (int mt = 0; mt < 4; ++mt)
      af[mt] = *(const bf16x8*)(&As[buf][((coh >> 4) + mt) * 512 + xo]);
#pragma unroll
    for (int nt = 0; nt < 4; ++nt)
      bfv[nt] = *(const bf16x8*)(&Bs[buf][((pxh >> 4) + nt) * 512 + xo]);
#pragma unroll
    for (int mt = 0; mt < 4; ++mt)
#pragma unroll
      for (int nt = 0; nt < 4; ++nt)
        acc[mt][nt] = __builtin_amdgcn_mfma_f32_16x16x32_bf16(af[mt], bfv[nt], acc[mt][nt], 0, 0, 0);
  };

  const int NCH = TC2 / 32;
  stage(0, 0);
  __syncthreads();
  for (int c = 0; c < NCH; ++c) {
    if (c < NCH - 1) stage(c + 1, (c + 1) & 1);
    comp(c & 1);
    if (c < NCH - 1) __syncthreads();
  }

#pragma unroll
  for (int mt = 0; mt < 4; ++mt) {
    int co = co_base + coh + mt * 16 + q * 4;
#pragma unroll
    for (int nt = 0; nt < 4; ++nt) {
      int pix = pix0 + pxh + nt * 16 + ln;
      int n = pix / (TH * TW);
      int hw = pix - n * (TH * TW);
#pragma unroll
      for (int r = 0; r < 4; ++r) {
        int addr = (n * TC2 + co + r) * (TH * TW) + hw;
        out[addr] = x[addr] + siluf(acc[mt][nt][r] + t3p[co + r]);
      }
    }
  }
}

extern "C" void kernel_launch(void* const* d_in, const int* in_sizes, int n_in,
                              void* d_out, int out_size, void* d_ws, size_t ws_size,
                              hipStream_t stream)
{
  const float* x    = (const float*)d_in[0];
  const float* w1   = (const float*)d_in[1];
  const float* g1   = (const float*)d_in[2];
  const float* b1   = (const float*)d_in[3];
  const float* m1   = (const float*)d_in[4];
  const float* v1   = (const float*)d_in[5];
  const float* w2   = (const float*)d_in[6];
  const float* g2   = (const float*)d_in[7];
  const float* b2   = (const float*)d_in[8];
  const float* m2   = (const float*)d_in[9];
  const float* v2   = (const float*)d_in[10];
  const float* dww  = (const float*)d_in[11];
  const float* dwb  = (const float*)d_in[12];
  const float* lng  = (const float*)d_in[13];
  const float* lnb  = (const float*)d_in[14];
  const float* offw = (const float*)d_in[15];
  const float* offb = (const float*)d_in[16];
  const float* mskw = (const float*)d_in[17];
  const float* mskb = (const float*)d_in[18];
  const float* inw  = (const float*)d_in[19];
  const float* inb  = (const float*)d_in[20];
  const float* outw = (const float*)d_in[21];
  const float* outb = (const float*)d_in[22];
  const float* g3   = (const float*)d_in[23];
  const float* b3   = (const float*)d_in[24];
  const float* m3   = (const float*)d_in[25];
  const float* v3   = (const float*)d_in[26];

  float* ws  = (float*)d_ws;
  float* out = (float*)d_out;

  short* xpn    = (short*)(ws + OFF_XPAD);
  short* wbf    = (short*)(ws + OFF_WBF);
  short* w2b    = (short*)(ws + OFF_W2B);
  short* inwb   = (short*)(ws + OFF_INWB);
  short* outwb  = (short*)(ws + OFF_OUTWB);
  short* wcat16 = (short*)(ws + OFF_WCAT);
  float* y1p    = ws + OFF_Y1P;
  short* y1b    = (short*)(ws + OFF_Y1B);
  short* y2b    = (short*)(ws + OFF_Y2N);
  short* dwo    = (short*)(ws + OFF_DWN);
  float* raw    = ws + OFF_RAWN;
  short* zb     = (short*)(ws + OFF_ZN);
  short* xproj  = (short*)d_out;

  hipLaunchKernelGGL(k_prep, dim3(1836), dim3(256), 0, stream,
                     w1, g1, b1, m1, v1, w2, g2, b2, m2, v2,
                     dww, offw, offb, mskw, mskb, inw, outw, outb, g3, b3, m3, v3, ws);
  hipLaunchKernelGGL(k_padx,     dim3(TN * THP * 8), dim3(256), 0, stream, x, xpn);
  hipLaunchKernelGGL(k_cv1,      dim3(600),   dim3(256), 0, stream, xpn, wbf, y1p);
  hipLaunchKernelGGL(k_y1red,    dim3(3200),  dim3(256), 0, stream, y1p, ws + OFF_T1, y1b);
  hipLaunchKernelGGL(k_cv2,      dim3(400),   dim3(256), 0, stream, y1b, w2b, ws + OFF_T2, y2b);
  hipLaunchKernelGGL(k_proj_in,  dim3(400),   dim3(256), 0, stream, y2b, inwb, inb, xproj);
  hipLaunchKernelGGL(k_dwln,     dim3(3200),  dim3(256), 0, stream, y2b, ws + OFF_DWT, dwb, lng, lnb, dwo);
  hipLaunchKernelGGL(k_offmask,  dim3(400),   dim3(256), 0, stream, dwo, wcat16, ws + OFF_WCATB, raw);
  hipLaunchKernelGGL(k_dcn,      dim3(3200),  dim3(256), 0, stream, xproj, raw, zb);
  hipLaunchKernelGGL(k_proj_out, dim3(400),   dim3(256), 0, stream, zb, outwb, ws + OFF_T3P, x, out);
}